// Round 2
// baseline (562.065 us; speedup 1.0000x reference)
//
#include <hip/hip_runtime.h>

// ---------- common helpers ----------
typedef short bf16x8 __attribute__((ext_vector_type(8)));
typedef float f32x4 __attribute__((ext_vector_type(4)));

__device__ __forceinline__ void async16(const void* g, const void* l) {
  __builtin_amdgcn_global_load_lds(
      (const __attribute__((address_space(1))) unsigned int*)g,
      (__attribute__((address_space(3))) unsigned int*)(void*)(uintptr_t)l,
      16, 0, 0);
}

__device__ __forceinline__ unsigned short f2b(float f) {
  unsigned int u = __float_as_uint(f);
  u += 0x7fffu + ((u >> 16) & 1u);   // round-to-nearest-even
  return (unsigned short)(u >> 16);
}

// ---------- cast fp32 -> bf16, n % 1024 == 0 ----------
__global__ __launch_bounds__(256) void cast_f32_bf16(
    const float* __restrict__ in, unsigned short* __restrict__ out, int n) {
  int i = (blockIdx.x * 256 + threadIdx.x) * 4;
  if (i < n) {
    float4 v = *(const float4*)(in + i);
    ushort4 o;
    o.x = f2b(v.x); o.y = f2b(v.y); o.z = f2b(v.z); o.w = f2b(v.w);
    *(ushort4*)(out + i) = o;
  }
}

// ---------- transpose+cast: out_bf16[N][K] = in_f32[K][N], K,N multiples of 64 ----------
__global__ __launch_bounds__(256) void transpose_cast(
    const float* __restrict__ in, unsigned short* __restrict__ out,
    int K, int N) {
  __shared__ __align__(16) unsigned short tile[64][65];
  const int k0 = blockIdx.y * 64, n0 = blockIdx.x * 64;
  const int tid = threadIdx.x;
  const int r = tid >> 4, c4 = tid & 15;
#pragma unroll
  for (int p = 0; p < 4; ++p) {
    int row = p * 16 + r;
    float4 v = *(const float4*)(in + (size_t)(k0 + row) * N + n0 + c4 * 4);
    tile[c4 * 4 + 0][row] = f2b(v.x);
    tile[c4 * 4 + 1][row] = f2b(v.y);
    tile[c4 * 4 + 2][row] = f2b(v.z);
    tile[c4 * 4 + 3][row] = f2b(v.w);
  }
  __syncthreads();
#pragma unroll
  for (int p = 0; p < 4; ++p) {
    int nr = p * 16 + r;
    ushort4 o;
    o.x = tile[nr][c4 * 4 + 0];
    o.y = tile[nr][c4 * 4 + 1];
    o.z = tile[nr][c4 * 4 + 2];
    o.w = tile[nr][c4 * 4 + 3];
    *(ushort4*)(out + (size_t)(n0 + nr) * K + k0 + c4 * 4) = o;
  }
}

// ---------- GEMM: C[M,N] = A[M,K] @ BT[N,K]^T (bf16 in, fp32 accum) ----------
// M%128==0, N%128==0, K%64==0. m97-style: 128x128 tile, BK=64, 4 waves 2x2.
// Cb (bf16) and/or Cf (fp32) outputs; either may be null.
__global__ __launch_bounds__(256) void gemm_bt(
    const unsigned short* __restrict__ A, const unsigned short* __restrict__ BT,
    unsigned short* __restrict__ Cb, float* __restrict__ Cf, int M, int N, int K) {
  __shared__ __align__(16) unsigned short sA[128 * 64];
  __shared__ __align__(16) unsigned short sB[128 * 64];
  const int tid = threadIdx.x;
  const int wave = tid >> 6, lane = tid & 63;
  const int quad = lane >> 4, cl = lane & 15;
  const int m0 = blockIdx.y * 128, n0 = blockIdx.x * 128;
  const int wm = (wave >> 1) * 64, wn = (wave & 1) * 64;
  (void)M;

  f32x4 acc[4][4] = {};

  const unsigned short* gA = A + (size_t)(m0 + wave * 32 + (lane >> 3)) * K + (lane & 7) * 8;
  const unsigned short* gB = BT + (size_t)(n0 + wave * 32 + (lane >> 3)) * K + (lane & 7) * 8;
  char* lA = (char*)sA + (wave * 32) * 128;
  char* lB = (char*)sB + (wave * 32) * 128;

  for (int kt = 0; kt < K; kt += 64) {
#pragma unroll
    for (int r = 0; r < 4; ++r) {
      async16(gA + (size_t)r * 8 * K + kt, lA + r * 8 * 128);
      async16(gB + (size_t)r * 8 * K + kt, lB + r * 8 * 128);
    }
    __syncthreads();
#pragma unroll
    for (int kk = 0; kk < 64; kk += 32) {
      bf16x8 af[4], bfr[4];
#pragma unroll
      for (int i = 0; i < 4; ++i)
        af[i] = *(const bf16x8*)((const char*)sA + (wm + i * 16 + cl) * 128 + kk * 2 + quad * 16);
#pragma unroll
      for (int j = 0; j < 4; ++j)
        bfr[j] = *(const bf16x8*)((const char*)sB + (wn + j * 16 + cl) * 128 + kk * 2 + quad * 16);
#pragma unroll
      for (int i = 0; i < 4; ++i)
#pragma unroll
        for (int j = 0; j < 4; ++j)
          acc[i][j] = __builtin_amdgcn_mfma_f32_16x16x32_bf16(af[i], bfr[j], acc[i][j], 0, 0, 0);
    }
    __syncthreads();
  }
#pragma unroll
  for (int i = 0; i < 4; ++i)
#pragma unroll
    for (int j = 0; j < 4; ++j)
#pragma unroll
      for (int r = 0; r < 4; ++r) {
        int row = m0 + wm + i * 16 + quad * 4 + r;
        int col = n0 + wn + j * 16 + cl;
        float v = acc[i][j][r];
        if (Cb) Cb[(size_t)row * N + col] = f2b(v);
        if (Cf) Cf[(size_t)row * N + col] = v;
      }
}

// ---------- flash-style causal attention (bf16 in/out) ----------
// grid: (T/128, H, B). Q/K/V/O are (B*T) x 2048 bf16, head h at cols h*128..
__global__ __launch_bounds__(256) void mla_attn(
    const unsigned short* __restrict__ Qm, const unsigned short* __restrict__ Km,
    const unsigned short* __restrict__ Vm, unsigned short* __restrict__ Om, int T) {
  const int ld = 2048;
  __shared__ __align__(16) unsigned short sQ[128 * 128];  // 32KB, resident
  __shared__ __align__(16) unsigned short sKP[64 * 128];  // 16KB: K tile [t][d], then P [q][t]
  __shared__ __align__(16) unsigned short sV[64 * 128];   // 16KB: V tile [t][d]
  const int qt = blockIdx.x, h = blockIdx.y, b = blockIdx.z;
  const int tid = threadIdx.x, wave = tid >> 6, lane = tid & 63;
  const int quad = lane >> 4, cl = lane & 15;

  // stage Q tile (async, drained by the first __syncthreads below)
  const unsigned short* Qg = Qm + (size_t)(b * T + qt * 128) * ld + h * 128;
#pragma unroll
  for (int r = 0; r < 8; ++r) {
    int row = wave * 32 + r * 4;  // + quad per lane
    async16(Qg + (size_t)(row + quad) * ld + cl * 8, (char*)sQ + row * 256);
  }

  float m_i[2][4], l_i[2][4];
  f32x4 acc_o[2][8] = {};
#pragma unroll
  for (int i = 0; i < 2; ++i)
#pragma unroll
    for (int r = 0; r < 4; ++r) { m_i[i][r] = -1e30f; l_i[i][r] = 0.f; }

  const int nkt = 2 * (qt + 1);
  const float scale = 0.08838834764831845f;  // 1/sqrt(128)

  for (int kt = 0; kt < nkt; ++kt) {
    const unsigned short* Kg = Km + (size_t)(b * T + kt * 64) * ld + h * 128;
    const unsigned short* Vg = Vm + (size_t)(b * T + kt * 64) * ld + h * 128;
    __syncthreads();  // previous tile fully consumed before restage
#pragma unroll
    for (int r = 0; r < 4; ++r) {
      int row = wave * 16 + r * 4;
      async16(Kg + (size_t)(row + quad) * ld + cl * 8, (char*)sKP + row * 256);
      async16(Vg + (size_t)(row + quad) * ld + cl * 8, (char*)sV + row * 256);
    }
    __syncthreads();  // staging complete

    // S = Q @ K^T  (rows wave*32..wave*32+31, cols 0..63 of this k-tile)
    f32x4 s[2][4] = {};
#pragma unroll
    for (int kk = 0; kk < 128; kk += 32) {
      bf16x8 aq[2];
#pragma unroll
      for (int i = 0; i < 2; ++i)
        aq[i] = *(const bf16x8*)((const char*)sQ + (wave * 32 + i * 16 + cl) * 256 + kk * 2 + quad * 16);
#pragma unroll
      for (int j = 0; j < 4; ++j) {
        bf16x8 bk = *(const bf16x8*)((const char*)sKP + (j * 16 + cl) * 256 + kk * 2 + quad * 16);
#pragma unroll
        for (int i = 0; i < 2; ++i)
          s[i][j] = __builtin_amdgcn_mfma_f32_16x16x32_bf16(aq[i], bk, s[i][j], 0, 0, 0);
      }
    }

    // scale + causal mask + online softmax (rows are wave-local: quad-group shuffles)
    const bool need_mask = (kt >= 2 * qt);
#pragma unroll
    for (int i = 0; i < 2; ++i) {
#pragma unroll
      for (int r = 0; r < 4; ++r) {
        int q_g = qt * 128 + wave * 32 + i * 16 + quad * 4 + r;
        float mx = -1e30f;
#pragma unroll
        for (int j = 0; j < 4; ++j) {
          float v = s[i][j][r] * scale;
          if (need_mask) {
            int t_g = kt * 64 + j * 16 + cl;
            if (t_g > q_g) v = -1e30f;
          }
          s[i][j][r] = v;
          mx = fmaxf(mx, v);
        }
#pragma unroll
        for (int off = 1; off < 16; off <<= 1)
          mx = fmaxf(mx, __shfl_xor(mx, off));
        float m_new = fmaxf(m_i[i][r], mx);
        float alpha = __expf(m_i[i][r] - m_new);
        m_i[i][r] = m_new;
        float rs = 0.f;
#pragma unroll
        for (int j = 0; j < 4; ++j) {
          float p = __expf(s[i][j][r] - m_new);
          s[i][j][r] = p;
          rs += p;
        }
#pragma unroll
        for (int off = 1; off < 16; off <<= 1)
          rs += __shfl_xor(rs, off);
        l_i[i][r] = l_i[i][r] * alpha + rs;
#pragma unroll
        for (int jd = 0; jd < 8; ++jd)
          acc_o[i][jd][r] *= alpha;
      }
    }

    __syncthreads();  // all waves done reading K before P overlays sKP

    // write P (bf16) into sKP as [q(128)][t(64)]
#pragma unroll
    for (int i = 0; i < 2; ++i)
#pragma unroll
      for (int j = 0; j < 4; ++j)
#pragma unroll
        for (int r = 0; r < 4; ++r)
          sKP[(wave * 32 + i * 16 + quad * 4 + r) * 64 + j * 16 + cl] = f2b(s[i][j][r]);

    // O += P @ V   (P rows are wave-local; in-wave ds ordering suffices)
#pragma unroll
    for (int kk2 = 0; kk2 < 2; ++kk2) {
      bf16x8 ap[2];
#pragma unroll
      for (int i = 0; i < 2; ++i)
        ap[i] = *(const bf16x8*)((const char*)sKP + (wave * 32 + i * 16 + cl) * 128 + kk2 * 64 + quad * 16);
#pragma unroll
      for (int jd = 0; jd < 8; ++jd) {
        bf16x8 bv;
#pragma unroll
        for (int jj = 0; jj < 8; ++jj)
          bv[jj] = (short)sV[(kk2 * 32 + quad * 8 + jj) * 128 + jd * 16 + cl];
#pragma unroll
        for (int i = 0; i < 2; ++i)
          acc_o[i][jd] = __builtin_amdgcn_mfma_f32_16x16x32_bf16(ap[i], bv, acc_o[i][jd], 0, 0, 0);
      }
    }
  }

  // epilogue: normalize and store
#pragma unroll
  for (int i = 0; i < 2; ++i)
#pragma unroll
    for (int r = 0; r < 4; ++r) {
      float inv = 1.f / l_i[i][r];
      int row = b * T + qt * 128 + wave * 32 + i * 16 + quad * 4 + r;
#pragma unroll
      for (int jd = 0; jd < 8; ++jd)
        Om[(size_t)row * ld + h * 128 + jd * 16 + cl] = f2b(acc_o[i][jd][r] * inv);
    }
}

// ---------- launch ----------
extern "C" void kernel_launch(void* const* d_in, const int* in_sizes, int n_in,
                              void* d_out, int out_size, void* d_ws, size_t ws_size,
                              hipStream_t stream) {
  (void)in_sizes; (void)n_in; (void)out_size; (void)ws_size;
  const int B = 2, T = 2048, Dm = 2048, H = 16, Dh = 128, R = 512;
  const int M = B * T;  // 4096
  const float* x     = (const float*)d_in[0];
  const float* Wq    = (const float*)d_in[1];
  const float* Wdown = (const float*)d_in[2];
  const float* Wkup  = (const float*)d_in[3];
  const float* Wvup  = (const float*)d_in[4];
  const float* Wo    = (const float*)d_in[5];

  float* out  = (float*)d_out;                      // (B*T) x 2048 fp32
  float* cout = out + (size_t)M * Dm;               // (B*T) x 512  fp32

  unsigned short* ws  = (unsigned short*)d_ws;      // bf16 scratch
  unsigned short* WqT = ws;                         // 2048x2048
  unsigned short* WoT = WqT + (size_t)Dm * Dm;      // 2048x2048
  unsigned short* WdT = WoT + (size_t)Dm * Dm;      // 512x2048
  unsigned short* WkT = WdT + (size_t)R * Dm;       // 2048x512
  unsigned short* WvT = WkT + (size_t)Dm * R;       // 2048x512
  unsigned short* xb  = WvT + (size_t)Dm * R;       // 4096x2048 (reused as AO)
  unsigned short* cb  = xb + (size_t)M * Dm;        // 4096x512
  unsigned short* Qb  = cb + (size_t)M * R;         // 4096x2048
  unsigned short* Kb  = Qb + (size_t)M * Dm;
  unsigned short* Vb  = Kb + (size_t)M * Dm;
  unsigned short* AO  = xb;                         // alias: xb dead after Q-proj

  // input casts / weight transposes -> bf16 BT form
  cast_f32_bf16<<<(M * Dm) / 1024, 256, 0, stream>>>(x, xb, M * Dm);
  transpose_cast<<<dim3(32, 32), 256, 0, stream>>>(Wq, WqT, Dm, Dm);
  transpose_cast<<<dim3(32, 32), 256, 0, stream>>>(Wo, WoT, Dm, Dm);
  transpose_cast<<<dim3(8, 32), 256, 0, stream>>>(Wdown, WdT, Dm, R);
  transpose_cast<<<dim3(32, 8), 256, 0, stream>>>(Wkup, WkT, R, Dm);
  transpose_cast<<<dim3(32, 8), 256, 0, stream>>>(Wvup, WvT, R, Dm);

  // projections
  gemm_bt<<<dim3(R / 128, M / 128), 256, 0, stream>>>(xb, WdT, cb, cout, M, R, Dm);     // c (bf16 + fp32 out)
  gemm_bt<<<dim3(Dm / 128, M / 128), 256, 0, stream>>>(xb, WqT, Qb, nullptr, M, Dm, Dm); // Q
  gemm_bt<<<dim3(Dm / 128, M / 128), 256, 0, stream>>>(cb, WkT, Kb, nullptr, M, Dm, R);  // K
  gemm_bt<<<dim3(Dm / 128, M / 128), 256, 0, stream>>>(cb, WvT, Vb, nullptr, M, Dm, R);  // V

  // causal attention (AO aliases xb; xb is dead after Q projection)
  mla_attn<<<dim3(T / 128, H, B), 256, 0, stream>>>(Qb, Kb, Vb, AO, T);

  // output projection (fp32 out)
  gemm_bt<<<dim3(Dm / 128, M / 128), 256, 0, stream>>>(AO, WoT, nullptr, out, M, Dm, Dm);
  (void)Dh; (void)H;
}

// Round 3
// 529.602 us; speedup vs baseline: 1.0613x; 1.0613x over previous
//
#include <hip/hip_runtime.h>

// ---------- common helpers ----------
typedef short bf16x8 __attribute__((ext_vector_type(8)));
typedef float f32x4 __attribute__((ext_vector_type(4)));

__device__ __forceinline__ void async16(const void* g, const void* l) {
  __builtin_amdgcn_global_load_lds(
      (const __attribute__((address_space(1))) unsigned int*)g,
      (__attribute__((address_space(3))) unsigned int*)(void*)(uintptr_t)l,
      16, 0, 0);
}

__device__ __forceinline__ unsigned short f2b(float f) {
  unsigned int u = __float_as_uint(f);
  u += 0x7fffu + ((u >> 16) & 1u);   // round-to-nearest-even
  return (unsigned short)(u >> 16);
}

// ---------- cast fp32 -> bf16, n % 1024 == 0 ----------
__global__ __launch_bounds__(256) void cast_f32_bf16(
    const float* __restrict__ in, unsigned short* __restrict__ out, int n) {
  int i = (blockIdx.x * 256 + threadIdx.x) * 4;
  if (i < n) {
    float4 v = *(const float4*)(in + i);
    ushort4 o;
    o.x = f2b(v.x); o.y = f2b(v.y); o.z = f2b(v.z); o.w = f2b(v.w);
    *(ushort4*)(out + i) = o;
  }
}

// ---------- transpose+cast: out_bf16[N][K] = in_f32[K][N], K,N multiples of 64 ----------
__global__ __launch_bounds__(256) void transpose_cast(
    const float* __restrict__ in, unsigned short* __restrict__ out,
    int K, int N) {
  __shared__ __align__(16) unsigned short tile[64][65];
  const int k0 = blockIdx.y * 64, n0 = blockIdx.x * 64;
  const int tid = threadIdx.x;
  const int r = tid >> 4, c4 = tid & 15;
#pragma unroll
  for (int p = 0; p < 4; ++p) {
    int row = p * 16 + r;
    float4 v = *(const float4*)(in + (size_t)(k0 + row) * N + n0 + c4 * 4);
    tile[c4 * 4 + 0][row] = f2b(v.x);
    tile[c4 * 4 + 1][row] = f2b(v.y);
    tile[c4 * 4 + 2][row] = f2b(v.z);
    tile[c4 * 4 + 3][row] = f2b(v.w);
  }
  __syncthreads();
#pragma unroll
  for (int p = 0; p < 4; ++p) {
    int nr = p * 16 + r;
    ushort4 o;
    o.x = tile[nr][c4 * 4 + 0];
    o.y = tile[nr][c4 * 4 + 1];
    o.z = tile[nr][c4 * 4 + 2];
    o.w = tile[nr][c4 * 4 + 3];
    *(ushort4*)(out + (size_t)(n0 + nr) * K + k0 + c4 * 4) = o;
  }
}

// ---------- transpose bf16: out[N][K] = in[K][N], K,N multiples of 64 ----------
__global__ __launch_bounds__(256) void transpose_bf16(
    const unsigned short* __restrict__ in, unsigned short* __restrict__ out,
    int K, int N) {
  __shared__ __align__(16) unsigned short tile[64][65];
  const int k0 = blockIdx.y * 64, n0 = blockIdx.x * 64;
  const int tid = threadIdx.x;
  const int r = tid >> 4, c4 = tid & 15;
#pragma unroll
  for (int p = 0; p < 4; ++p) {
    int row = p * 16 + r;
    ushort4 v = *(const ushort4*)(in + (size_t)(k0 + row) * N + n0 + c4 * 4);
    tile[c4 * 4 + 0][row] = v.x;
    tile[c4 * 4 + 1][row] = v.y;
    tile[c4 * 4 + 2][row] = v.z;
    tile[c4 * 4 + 3][row] = v.w;
  }
  __syncthreads();
#pragma unroll
  for (int p = 0; p < 4; ++p) {
    int nr = p * 16 + r;
    ushort4 o;
    o.x = tile[nr][c4 * 4 + 0];
    o.y = tile[nr][c4 * 4 + 1];
    o.z = tile[nr][c4 * 4 + 2];
    o.w = tile[nr][c4 * 4 + 3];
    *(ushort4*)(out + (size_t)(n0 + nr) * K + k0 + c4 * 4) = o;
  }
}

// ---------- GEMM: C[M,N] = A[M,K] @ BT[N,K]^T (bf16 in, fp32 accum) ----------
// M%128==0, N%128==0, K%64==0. m97-style: 128x128 tile, BK=64, 4 waves 2x2.
__global__ __launch_bounds__(256) void gemm_bt(
    const unsigned short* __restrict__ A, const unsigned short* __restrict__ BT,
    unsigned short* __restrict__ Cb, float* __restrict__ Cf, int M, int N, int K) {
  __shared__ __align__(16) unsigned short sA[128 * 64];
  __shared__ __align__(16) unsigned short sB[128 * 64];
  const int tid = threadIdx.x;
  const int wave = tid >> 6, lane = tid & 63;
  const int quad = lane >> 4, cl = lane & 15;
  const int m0 = blockIdx.y * 128, n0 = blockIdx.x * 128;
  const int wm = (wave >> 1) * 64, wn = (wave & 1) * 64;
  (void)M;

  f32x4 acc[4][4] = {};

  const unsigned short* gA = A + (size_t)(m0 + wave * 32 + (lane >> 3)) * K + (lane & 7) * 8;
  const unsigned short* gB = BT + (size_t)(n0 + wave * 32 + (lane >> 3)) * K + (lane & 7) * 8;
  char* lA = (char*)sA + (wave * 32) * 128;
  char* lB = (char*)sB + (wave * 32) * 128;

  for (int kt = 0; kt < K; kt += 64) {
#pragma unroll
    for (int r = 0; r < 4; ++r) {
      async16(gA + (size_t)r * 8 * K + kt, lA + r * 8 * 128);
      async16(gB + (size_t)r * 8 * K + kt, lB + r * 8 * 128);
    }
    __syncthreads();
#pragma unroll
    for (int kk = 0; kk < 64; kk += 32) {
      bf16x8 af[4], bfr[4];
#pragma unroll
      for (int i = 0; i < 4; ++i)
        af[i] = *(const bf16x8*)((const char*)sA + (wm + i * 16 + cl) * 128 + kk * 2 + quad * 16);
#pragma unroll
      for (int j = 0; j < 4; ++j)
        bfr[j] = *(const bf16x8*)((const char*)sB + (wn + j * 16 + cl) * 128 + kk * 2 + quad * 16);
#pragma unroll
      for (int i = 0; i < 4; ++i)
#pragma unroll
        for (int j = 0; j < 4; ++j)
          acc[i][j] = __builtin_amdgcn_mfma_f32_16x16x32_bf16(af[i], bfr[j], acc[i][j], 0, 0, 0);
    }
    __syncthreads();
  }
#pragma unroll
  for (int i = 0; i < 4; ++i)
#pragma unroll
    for (int j = 0; j < 4; ++j)
#pragma unroll
      for (int r = 0; r < 4; ++r) {
        int row = m0 + wm + i * 16 + quad * 4 + r;
        int col = n0 + wn + j * 16 + cl;
        float v = acc[i][j][r];
        if (Cb) Cb[(size_t)row * N + col] = f2b(v);
        if (Cf) Cf[(size_t)row * N + col] = v;
      }
}

// ---------- flash-style causal attention, v2 ----------
// grid: (T/128, H, B). Q/K are (B*T)x2048 bf16; Vt is 2048x(B*T) bf16 (d-major).
// All LDS tiles XOR-chunk-swizzled: chunk j at row r lives at position j^(r&7).
__global__ __launch_bounds__(256) void mla_attn(
    const unsigned short* __restrict__ Qm, const unsigned short* __restrict__ Km,
    const unsigned short* __restrict__ Vt, unsigned short* __restrict__ Om, int T) {
  const int ld = 2048;
  const int ldv = 4096;  // B*T
  __shared__ __align__(16) unsigned short sQ[128 * 128];  // 32KB [q][d] pitch 16 chunks
  __shared__ __align__(16) unsigned short sK[64 * 128];   // 16KB [t][d] pitch 16 chunks
  __shared__ __align__(16) unsigned short sVT[128 * 64];  // 16KB [d][t] pitch 8 chunks
  __shared__ __align__(16) unsigned short sP[128 * 64];   // 16KB [q][t] pitch 8 chunks
  const int nq = gridDim.x;
  const int bx = blockIdx.x;
  const int qt = (bx & 1) ? (bx >> 1) : (nq - 1 - (bx >> 1));  // heavy+light pairing
  const int h = blockIdx.y, b = blockIdx.z;
  const int tid = threadIdx.x, wave = tid >> 6, lane = tid & 63;
  const int quad = lane >> 4, cl = lane & 15;

  // stage Q tile (swizzled; drained by first in-loop barrier)
  const unsigned short* Qg = Qm + (size_t)(b * T + qt * 128) * ld + h * 128;
#pragma unroll
  for (int r = 0; r < 8; ++r) {
    int c0 = r * 256 + wave * 64;
    int c = c0 + lane;
    int row = c >> 4, j = (c & 15) ^ (row & 7);
    async16(Qg + (size_t)row * ld + j * 8, (char*)sQ + c0 * 16);
  }

  float m_i[2][4], l_i[2][4];
  f32x4 acc_o[2][8] = {};
#pragma unroll
  for (int i = 0; i < 2; ++i)
#pragma unroll
    for (int r = 0; r < 4; ++r) { m_i[i][r] = -1e30f; l_i[i][r] = 0.f; }

  const int nkt = 2 * (qt + 1);
  const float scale = 0.08838834764831845f;  // 1/sqrt(128)

  for (int kt = 0; kt < nkt; ++kt) {
    const unsigned short* Kg = Km + (size_t)(b * T + kt * 64) * ld + h * 128;
    const unsigned short* Vg = Vt + (size_t)(h * 128) * ldv + (size_t)b * T + kt * 64;
    __syncthreads();  // previous tile's sK/sVT reads complete
#pragma unroll
    for (int r = 0; r < 4; ++r) {
      int c0 = r * 256 + wave * 64;
      int c = c0 + lane;
      int row = c >> 4, j = (c & 15) ^ (row & 7);
      async16(Kg + (size_t)row * ld + j * 8, (char*)sK + c0 * 16);
      int d = c >> 3, jv = (c & 7) ^ (d & 7);
      async16(Vg + (size_t)d * ldv + jv * 8, (char*)sVT + c0 * 16);
    }
    __syncthreads();  // staging complete (barrier drains vmcnt)

    // S = Q @ K^T
    f32x4 s[2][4] = {};
#pragma unroll
    for (int kk = 0; kk < 4; ++kk) {  // k-offset = kk*32 elems = chunk base kk*4
      bf16x8 aq[2];
#pragma unroll
      for (int i = 0; i < 2; ++i) {
        int q = wave * 32 + i * 16 + cl;
        int jp = (kk * 4 + quad) ^ (q & 7);
        aq[i] = *(const bf16x8*)((const char*)sQ + (q * 16 + jp) * 16);
      }
#pragma unroll
      for (int j = 0; j < 4; ++j) {
        int t = j * 16 + cl;
        int jp = (kk * 4 + quad) ^ (t & 7);
        bf16x8 bk = *(const bf16x8*)((const char*)sK + (t * 16 + jp) * 16);
#pragma unroll
        for (int i = 0; i < 2; ++i)
          s[i][j] = __builtin_amdgcn_mfma_f32_16x16x32_bf16(aq[i], bk, s[i][j], 0, 0, 0);
      }
    }

    // scale + causal mask + online softmax (rows wave-local: quad-group shuffles)
    const bool need_mask = (kt >= 2 * qt);
#pragma unroll
    for (int i = 0; i < 2; ++i) {
#pragma unroll
      for (int r = 0; r < 4; ++r) {
        int q_g = qt * 128 + wave * 32 + i * 16 + quad * 4 + r;
        float mx = -1e30f;
#pragma unroll
        for (int j = 0; j < 4; ++j) {
          float v = s[i][j][r] * scale;
          if (need_mask) {
            int t_g = kt * 64 + j * 16 + cl;
            if (t_g > q_g) v = -1e30f;
          }
          s[i][j][r] = v;
          mx = fmaxf(mx, v);
        }
#pragma unroll
        for (int off = 1; off < 16; off <<= 1)
          mx = fmaxf(mx, __shfl_xor(mx, off));
        float m_new = fmaxf(m_i[i][r], mx);
        float alpha = __expf(m_i[i][r] - m_new);
        m_i[i][r] = m_new;
        float rs = 0.f;
#pragma unroll
        for (int j = 0; j < 4; ++j) {
          float p = __expf(s[i][j][r] - m_new);
          s[i][j][r] = p;
          rs += p;
        }
#pragma unroll
        for (int off = 1; off < 16; off <<= 1)
          rs += __shfl_xor(rs, off);
        l_i[i][r] = l_i[i][r] * alpha + rs;
#pragma unroll
        for (int jd = 0; jd < 8; ++jd)
          acc_o[i][jd][r] *= alpha;
      }
    }

    // write P (bf16) swizzled into sP [q][t] — wave-local rows, no barrier needed
#pragma unroll
    for (int i = 0; i < 2; ++i)
#pragma unroll
      for (int j = 0; j < 4; ++j)
#pragma unroll
        for (int r = 0; r < 4; ++r) {
          int q = wave * 32 + i * 16 + quad * 4 + r;
          int t = j * 16 + cl;
          int jp = (t >> 3) ^ (q & 7);
          sP[(q * 8 + jp) * 8 + (t & 7)] = f2b(s[i][j][r]);
        }

    // O += P @ V  (A from sP own-wave rows, B from sVT — both b128, conflict-free)
#pragma unroll
    for (int kk2 = 0; kk2 < 2; ++kk2) {
      bf16x8 ap[2];
#pragma unroll
      for (int i = 0; i < 2; ++i) {
        int q = wave * 32 + i * 16 + cl;
        int jp = (kk2 * 4 + quad) ^ (q & 7);
        ap[i] = *(const bf16x8*)((const char*)sP + (q * 8 + jp) * 16);
      }
#pragma unroll
      for (int jd = 0; jd < 8; ++jd) {
        int d = jd * 16 + cl;
        int jp = (kk2 * 4 + quad) ^ (d & 7);
        bf16x8 bv = *(const bf16x8*)((const char*)sVT + (d * 8 + jp) * 16);
#pragma unroll
        for (int i = 0; i < 2; ++i)
          acc_o[i][jd] = __builtin_amdgcn_mfma_f32_16x16x32_bf16(ap[i], bv, acc_o[i][jd], 0, 0, 0);
      }
    }
  }

  // epilogue: normalize and store
#pragma unroll
  for (int i = 0; i < 2; ++i)
#pragma unroll
    for (int r = 0; r < 4; ++r) {
      float inv = 1.f / l_i[i][r];
      int row = b * T + qt * 128 + wave * 32 + i * 16 + quad * 4 + r;
#pragma unroll
      for (int jd = 0; jd < 8; ++jd)
        Om[(size_t)row * ld + h * 128 + jd * 16 + cl] = f2b(acc_o[i][jd][r] * inv);
    }
}

// ---------- launch ----------
extern "C" void kernel_launch(void* const* d_in, const int* in_sizes, int n_in,
                              void* d_out, int out_size, void* d_ws, size_t ws_size,
                              hipStream_t stream) {
  (void)in_sizes; (void)n_in; (void)out_size; (void)ws_size;
  const int B = 2, T = 2048, Dm = 2048, H = 16, Dh = 128, R = 512;
  const int M = B * T;  // 4096
  const float* x     = (const float*)d_in[0];
  const float* Wq    = (const float*)d_in[1];
  const float* Wdown = (const float*)d_in[2];
  const float* Wkup  = (const float*)d_in[3];
  const float* Wvup  = (const float*)d_in[4];
  const float* Wo    = (const float*)d_in[5];

  float* out  = (float*)d_out;                      // (B*T) x 2048 fp32
  float* cout = out + (size_t)M * Dm;               // (B*T) x 512  fp32

  unsigned short* ws  = (unsigned short*)d_ws;      // bf16 scratch
  unsigned short* WqT = ws;                         // 2048x2048
  unsigned short* WoT = WqT + (size_t)Dm * Dm;      // 2048x2048
  unsigned short* WdT = WoT + (size_t)Dm * Dm;      // 512x2048
  unsigned short* WkT = WdT + (size_t)R * Dm;       // 2048x512
  unsigned short* WvT = WkT + (size_t)Dm * R;       // 2048x512
  unsigned short* xb  = WvT + (size_t)Dm * R;       // 4096x2048 (reused as AO)
  unsigned short* cb  = xb + (size_t)M * Dm;        // 4096x512
  unsigned short* Qb  = cb + (size_t)M * R;         // 4096x2048
  unsigned short* Kb  = Qb + (size_t)M * Dm;
  unsigned short* Vb  = Kb + (size_t)M * Dm;
  unsigned short* Vtb = Vb + (size_t)M * Dm;        // 2048x4096 (V^T, d-major)
  unsigned short* AO  = xb;                         // alias: xb dead after Q-proj

  // input casts / weight transposes -> bf16 BT form
  cast_f32_bf16<<<(M * Dm) / 1024, 256, 0, stream>>>(x, xb, M * Dm);
  transpose_cast<<<dim3(32, 32), 256, 0, stream>>>(Wq, WqT, Dm, Dm);
  transpose_cast<<<dim3(32, 32), 256, 0, stream>>>(Wo, WoT, Dm, Dm);
  transpose_cast<<<dim3(8, 32), 256, 0, stream>>>(Wdown, WdT, Dm, R);
  transpose_cast<<<dim3(32, 8), 256, 0, stream>>>(Wkup, WkT, R, Dm);
  transpose_cast<<<dim3(32, 8), 256, 0, stream>>>(Wvup, WvT, R, Dm);

  // projections
  gemm_bt<<<dim3(R / 128, M / 128), 256, 0, stream>>>(xb, WdT, cb, cout, M, R, Dm);      // c
  gemm_bt<<<dim3(Dm / 128, M / 128), 256, 0, stream>>>(xb, WqT, Qb, nullptr, M, Dm, Dm); // Q
  gemm_bt<<<dim3(Dm / 128, M / 128), 256, 0, stream>>>(cb, WkT, Kb, nullptr, M, Dm, R);  // K
  gemm_bt<<<dim3(Dm / 128, M / 128), 256, 0, stream>>>(cb, WvT, Vb, nullptr, M, Dm, R);  // V

  // V -> V^T (d-major) for conflict-free PV B-fragments
  transpose_bf16<<<dim3(Dm / 64, M / 64), 256, 0, stream>>>(Vb, Vtb, M, Dm);

  // causal attention (AO aliases xb; xb dead after Q projection)
  mla_attn<<<dim3(T / 128, H, B), 256, 0, stream>>>(Qb, Kb, Vtb, AO, T);

  // output projection (fp32 out)
  gemm_bt<<<dim3(Dm / 128, M / 128), 256, 0, stream>>>(AO, WoT, nullptr, out, M, Dm, Dm);
  (void)Dh; (void)H;
}

// Round 4
// 427.952 us; speedup vs baseline: 1.3134x; 1.2375x over previous
//
#include <hip/hip_runtime.h>

// ---------- common helpers ----------
typedef short bf16x8 __attribute__((ext_vector_type(8)));
typedef float f32x4 __attribute__((ext_vector_type(4)));

__device__ __forceinline__ void async16(const void* g, const void* l) {
  __builtin_amdgcn_global_load_lds(
      (const __attribute__((address_space(1))) unsigned int*)g,
      (__attribute__((address_space(3))) unsigned int*)(void*)(uintptr_t)l,
      16, 0, 0);
}

__device__ __forceinline__ unsigned short f2b(float f) {
  unsigned int u = __float_as_uint(f);
  u += 0x7fffu + ((u >> 16) & 1u);   // round-to-nearest-even
  return (unsigned short)(u >> 16);
}

// ---------- cast fp32 -> bf16, n % 1024 == 0 ----------
__global__ __launch_bounds__(256) void cast_f32_bf16(
    const float* __restrict__ in, unsigned short* __restrict__ out, int n) {
  int i = (blockIdx.x * 256 + threadIdx.x) * 4;
  if (i < n) {
    float4 v = *(const float4*)(in + i);
    ushort4 o;
    o.x = f2b(v.x); o.y = f2b(v.y); o.z = f2b(v.z); o.w = f2b(v.w);
    *(ushort4*)(out + i) = o;
  }
}

// ---------- transpose+cast: out_bf16[N][K] = in_f32[K][N], K,N multiples of 64 ----------
__global__ __launch_bounds__(256) void transpose_cast(
    const float* __restrict__ in, unsigned short* __restrict__ out,
    int K, int N) {
  __shared__ __align__(16) unsigned short tile[64][65];
  const int k0 = blockIdx.y * 64, n0 = blockIdx.x * 64;
  const int tid = threadIdx.x;
  const int r = tid >> 4, c4 = tid & 15;
#pragma unroll
  for (int p = 0; p < 4; ++p) {
    int row = p * 16 + r;
    float4 v = *(const float4*)(in + (size_t)(k0 + row) * N + n0 + c4 * 4);
    tile[c4 * 4 + 0][row] = f2b(v.x);
    tile[c4 * 4 + 1][row] = f2b(v.y);
    tile[c4 * 4 + 2][row] = f2b(v.z);
    tile[c4 * 4 + 3][row] = f2b(v.w);
  }
  __syncthreads();
#pragma unroll
  for (int p = 0; p < 4; ++p) {
    int nr = p * 16 + r;
    ushort4 o;
    o.x = tile[nr][c4 * 4 + 0];
    o.y = tile[nr][c4 * 4 + 1];
    o.z = tile[nr][c4 * 4 + 2];
    o.w = tile[nr][c4 * 4 + 3];
    *(ushort4*)(out + (size_t)(n0 + nr) * K + k0 + c4 * 4) = o;
  }
}

// ---------- transpose bf16: out[N][K] = in[K][N], K,N multiples of 64 ----------
__global__ __launch_bounds__(256) void transpose_bf16(
    const unsigned short* __restrict__ in, unsigned short* __restrict__ out,
    int K, int N) {
  __shared__ __align__(16) unsigned short tile[64][65];
  const int k0 = blockIdx.y * 64, n0 = blockIdx.x * 64;
  const int tid = threadIdx.x;
  const int r = tid >> 4, c4 = tid & 15;
#pragma unroll
  for (int p = 0; p < 4; ++p) {
    int row = p * 16 + r;
    ushort4 v = *(const ushort4*)(in + (size_t)(k0 + row) * N + n0 + c4 * 4);
    tile[c4 * 4 + 0][row] = v.x;
    tile[c4 * 4 + 1][row] = v.y;
    tile[c4 * 4 + 2][row] = v.z;
    tile[c4 * 4 + 3][row] = v.w;
  }
  __syncthreads();
#pragma unroll
  for (int p = 0; p < 4; ++p) {
    int nr = p * 16 + r;
    ushort4 o;
    o.x = tile[nr][c4 * 4 + 0];
    o.y = tile[nr][c4 * 4 + 1];
    o.z = tile[nr][c4 * 4 + 2];
    o.w = tile[nr][c4 * 4 + 3];
    *(ushort4*)(out + (size_t)(n0 + nr) * K + k0 + c4 * 4) = o;
  }
}

// ---------- GEMM: C[M,N] = A[M,K] @ BT[N,K]^T (bf16 in, fp32 accum) ----------
// M%128==0, N%128==0, K%64==0. m97-style: 128x128 tile, BK=64, 4 waves 2x2.
__global__ __launch_bounds__(256) void gemm_bt(
    const unsigned short* __restrict__ A, const unsigned short* __restrict__ BT,
    unsigned short* __restrict__ Cb, float* __restrict__ Cf, int M, int N, int K) {
  __shared__ __align__(16) unsigned short sA[128 * 64];
  __shared__ __align__(16) unsigned short sB[128 * 64];
  const int tid = threadIdx.x;
  const int wave = tid >> 6, lane = tid & 63;
  const int quad = lane >> 4, cl = lane & 15;
  const int m0 = blockIdx.y * 128, n0 = blockIdx.x * 128;
  const int wm = (wave >> 1) * 64, wn = (wave & 1) * 64;
  (void)M;

  f32x4 acc[4][4] = {};

  const unsigned short* gA = A + (size_t)(m0 + wave * 32 + (lane >> 3)) * K + (lane & 7) * 8;
  const unsigned short* gB = BT + (size_t)(n0 + wave * 32 + (lane >> 3)) * K + (lane & 7) * 8;
  char* lA = (char*)sA + (wave * 32) * 128;
  char* lB = (char*)sB + (wave * 32) * 128;

  for (int kt = 0; kt < K; kt += 64) {
#pragma unroll
    for (int r = 0; r < 4; ++r) {
      async16(gA + (size_t)r * 8 * K + kt, lA + r * 8 * 128);
      async16(gB + (size_t)r * 8 * K + kt, lB + r * 8 * 128);
    }
    __syncthreads();
#pragma unroll
    for (int kk = 0; kk < 64; kk += 32) {
      bf16x8 af[4], bfr[4];
#pragma unroll
      for (int i = 0; i < 4; ++i)
        af[i] = *(const bf16x8*)((const char*)sA + (wm + i * 16 + cl) * 128 + kk * 2 + quad * 16);
#pragma unroll
      for (int j = 0; j < 4; ++j)
        bfr[j] = *(const bf16x8*)((const char*)sB + (wn + j * 16 + cl) * 128 + kk * 2 + quad * 16);
#pragma unroll
      for (int i = 0; i < 4; ++i)
#pragma unroll
        for (int j = 0; j < 4; ++j)
          acc[i][j] = __builtin_amdgcn_mfma_f32_16x16x32_bf16(af[i], bfr[j], acc[i][j], 0, 0, 0);
    }
    __syncthreads();
  }
#pragma unroll
  for (int i = 0; i < 4; ++i)
#pragma unroll
    for (int j = 0; j < 4; ++j)
#pragma unroll
      for (int r = 0; r < 4; ++r) {
        int row = m0 + wm + i * 16 + quad * 4 + r;
        int col = n0 + wn + j * 16 + cl;
        float v = acc[i][j][r];
        if (Cb) Cb[(size_t)row * N + col] = f2b(v);
        if (Cf) Cf[(size_t)row * N + col] = v;
      }
}

// ---------- flash-style causal attention, v3 ----------
// grid: (T/128, H, B) = (16,16,2), 256 threads. Each block processes the
// balanced q-tile pair {bx, 31-bx} (64-row tiles) sequentially: every block
// does exactly 33 k-tiles -> zero tail. Q lives in registers (no sQ).
// LDS 40KB: sK 16K + sVT 16K + sP 8K.
__global__ __launch_bounds__(256) void mla_attn(
    const unsigned short* __restrict__ Qm, const unsigned short* __restrict__ Km,
    const unsigned short* __restrict__ Vt, unsigned short* __restrict__ Om, int T) {
  const int ld = 2048;
  const int ldv = 4096;  // B*T
  __shared__ __align__(16) unsigned short sK[64 * 128];   // [t][d] 16 chunks/row, xor-swizzled
  __shared__ __align__(16) unsigned short sVT[128 * 64];  // [d][t] 8 chunks/row, xor-swizzled
  __shared__ __align__(16) unsigned short sP[64 * 64];    // [q][t] 8 chunks/row, swz(q)-swizzled
  const int h = blockIdx.y, b = blockIdx.z;
  const int tid = threadIdx.x, wave = tid >> 6, lane = tid & 63;
  const int quad = lane >> 4, cl = lane & 15;
  const int nq = T / 64;  // 32
  // fold 1/sqrt(128) * log2(e) : softmax computed in exp2 domain
  const float scale2 = 0.08838834764831845f * 1.4426950408889634f;

  for (int phase = 0; phase < 2; ++phase) {
    const int qt = phase ? (nq - 1 - blockIdx.x) : blockIdx.x;

    // Q A-fragments in registers: rows wave*16+cl, k = kk*32 + quad*8 + jj
    bf16x8 qf[4];
    {
      const unsigned short* Qg =
          Qm + (size_t)(b * T + qt * 64 + wave * 16 + cl) * ld + h * 128 + quad * 8;
#pragma unroll
      for (int kk = 0; kk < 4; ++kk)
        qf[kk] = *(const bf16x8*)(Qg + kk * 32);
    }

    float m_i[4], l_i[4];
    f32x4 acc_o[8] = {};
#pragma unroll
    for (int r = 0; r < 4; ++r) { m_i[r] = -1e30f; l_i[r] = 0.f; }

    for (int kt = 0; kt <= qt; ++kt) {
      const unsigned short* Kg = Km + (size_t)(b * T + kt * 64) * ld + h * 128;
      const unsigned short* Vg = Vt + (size_t)(h * 128) * ldv + (size_t)b * T + kt * 64;
      __syncthreads();  // previous tile's sK/sVT reads complete
#pragma unroll
      for (int r = 0; r < 4; ++r) {
        int c0 = r * 256 + wave * 64;
        int c = c0 + lane;
        int row = c >> 4, j = (c & 15) ^ (row & 7);
        async16(Kg + (size_t)row * ld + j * 8, (char*)sK + c0 * 16);
        int d = c >> 3, jv = (c & 7) ^ (d & 7);
        async16(Vg + (size_t)d * ldv + jv * 8, (char*)sVT + c0 * 16);
      }
      __syncthreads();  // staging complete

      // S = Q @ K^T : 16 q-rows (this wave) x 64 keys
      f32x4 s[4] = {};
#pragma unroll
      for (int kk = 0; kk < 4; ++kk) {
#pragma unroll
        for (int j = 0; j < 4; ++j) {
          int t = j * 16 + cl;
          int jp = (kk * 4 + quad) ^ (t & 7);
          bf16x8 bk = *(const bf16x8*)((const char*)sK + (t * 16 + jp) * 16);
          s[j] = __builtin_amdgcn_mfma_f32_16x16x32_bf16(qf[kk], bk, s[j], 0, 0, 0);
        }
      }

      // scale (exp2 domain) + causal mask + online softmax
      const bool need_mask = (kt == qt);
#pragma unroll
      for (int r = 0; r < 4; ++r) {
        int q_l = wave * 16 + quad * 4 + r;  // local q row (tile row)
        float mx = -1e30f;
#pragma unroll
        for (int j = 0; j < 4; ++j) {
          float v = s[j][r] * scale2;
          if (need_mask) {
            int t_l = j * 16 + cl;
            if (t_l > q_l) v = -1e30f;
          }
          s[j][r] = v;
          mx = fmaxf(mx, v);
        }
#pragma unroll
        for (int off = 1; off < 16; off <<= 1)
          mx = fmaxf(mx, __shfl_xor(mx, off));
        float m_new = fmaxf(m_i[r], mx);
        float alpha = exp2f(m_i[r] - m_new);
        m_i[r] = m_new;
        float rs = 0.f;
#pragma unroll
        for (int j = 0; j < 4; ++j) {
          float p = exp2f(s[j][r] - m_new);
          s[j][r] = p;
          rs += p;
        }
#pragma unroll
        for (int off = 1; off < 16; off <<= 1)
          rs += __shfl_xor(rs, off);
        l_i[r] = l_i[r] * alpha + rs;
#pragma unroll
        for (int jd = 0; jd < 8; ++jd)
          acc_o[jd][r] *= alpha;
      }

      // write P swizzled into sP (wave-local rows -> no barrier needed)
      // swz(q) = (q&7) ^ (((q>>3)&1)<<1): all 4 quads hit disjoint bank sets
#pragma unroll
      for (int j = 0; j < 4; ++j)
#pragma unroll
        for (int r = 0; r < 4; ++r) {
          int q = wave * 16 + quad * 4 + r;
          int swz = (q & 7) ^ (((q >> 3) & 1) << 1);
          int t = j * 16 + cl;
          int jp = (t >> 3) ^ swz;
          sP[(q * 8 + jp) * 8 + (t & 7)] = f2b(s[j][r]);
        }

      // O += P @ V (A from own-wave sP rows, B from sVT; both b128)
#pragma unroll
      for (int kk2 = 0; kk2 < 2; ++kk2) {
        int q = wave * 16 + cl;
        int swz = (q & 7) ^ (((q >> 3) & 1) << 1);
        int jp = (kk2 * 4 + quad) ^ swz;
        bf16x8 ap = *(const bf16x8*)((const char*)sP + (q * 8 + jp) * 16);
#pragma unroll
        for (int jd = 0; jd < 8; ++jd) {
          int d = jd * 16 + cl;
          int jpv = (kk2 * 4 + quad) ^ (d & 7);
          bf16x8 bv = *(const bf16x8*)((const char*)sVT + (d * 8 + jpv) * 16);
          acc_o[jd] = __builtin_amdgcn_mfma_f32_16x16x32_bf16(ap, bv, acc_o[jd], 0, 0, 0);
        }
      }
    }

    // epilogue: normalize and store this q-tile
#pragma unroll
    for (int r = 0; r < 4; ++r) {
      float inv = 1.f / l_i[r];
      int row = b * T + qt * 64 + wave * 16 + quad * 4 + r;
#pragma unroll
      for (int jd = 0; jd < 8; ++jd)
        Om[(size_t)row * ld + h * 128 + jd * 16 + cl] = f2b(acc_o[jd][r] * inv);
    }
  }
}

// ---------- launch ----------
extern "C" void kernel_launch(void* const* d_in, const int* in_sizes, int n_in,
                              void* d_out, int out_size, void* d_ws, size_t ws_size,
                              hipStream_t stream) {
  (void)in_sizes; (void)n_in; (void)out_size; (void)ws_size;
  const int B = 2, T = 2048, Dm = 2048, H = 16, Dh = 128, R = 512;
  const int M = B * T;  // 4096
  const float* x     = (const float*)d_in[0];
  const float* Wq    = (const float*)d_in[1];
  const float* Wdown = (const float*)d_in[2];
  const float* Wkup  = (const float*)d_in[3];
  const float* Wvup  = (const float*)d_in[4];
  const float* Wo    = (const float*)d_in[5];

  float* out  = (float*)d_out;                      // (B*T) x 2048 fp32
  float* cout = out + (size_t)M * Dm;               // (B*T) x 512  fp32

  unsigned short* ws  = (unsigned short*)d_ws;      // bf16 scratch
  unsigned short* WqT = ws;                         // 2048x2048
  unsigned short* WoT = WqT + (size_t)Dm * Dm;      // 2048x2048
  unsigned short* WdT = WoT + (size_t)Dm * Dm;      // 512x2048
  unsigned short* WkT = WdT + (size_t)R * Dm;       // 2048x512
  unsigned short* WvT = WkT + (size_t)Dm * R;       // 2048x512
  unsigned short* xb  = WvT + (size_t)Dm * R;       // 4096x2048 (reused as AO)
  unsigned short* cb  = xb + (size_t)M * Dm;        // 4096x512
  unsigned short* Qb  = cb + (size_t)M * R;         // 4096x2048
  unsigned short* Kb  = Qb + (size_t)M * Dm;
  unsigned short* Vb  = Kb + (size_t)M * Dm;
  unsigned short* Vtb = Vb + (size_t)M * Dm;        // 2048x4096 (V^T, d-major)
  unsigned short* AO  = xb;                         // alias: xb dead after Q-proj

  // input casts / weight transposes -> bf16 BT form
  cast_f32_bf16<<<(M * Dm) / 1024, 256, 0, stream>>>(x, xb, M * Dm);
  transpose_cast<<<dim3(32, 32), 256, 0, stream>>>(Wq, WqT, Dm, Dm);
  transpose_cast<<<dim3(32, 32), 256, 0, stream>>>(Wo, WoT, Dm, Dm);
  transpose_cast<<<dim3(8, 32), 256, 0, stream>>>(Wdown, WdT, Dm, R);
  transpose_cast<<<dim3(32, 8), 256, 0, stream>>>(Wkup, WkT, R, Dm);
  transpose_cast<<<dim3(32, 8), 256, 0, stream>>>(Wvup, WvT, R, Dm);

  // projections
  gemm_bt<<<dim3(R / 128, M / 128), 256, 0, stream>>>(xb, WdT, cb, cout, M, R, Dm);      // c
  gemm_bt<<<dim3(Dm / 128, M / 128), 256, 0, stream>>>(xb, WqT, Qb, nullptr, M, Dm, Dm); // Q
  gemm_bt<<<dim3(Dm / 128, M / 128), 256, 0, stream>>>(cb, WkT, Kb, nullptr, M, Dm, R);  // K
  gemm_bt<<<dim3(Dm / 128, M / 128), 256, 0, stream>>>(cb, WvT, Vb, nullptr, M, Dm, R);  // V

  // V -> V^T (d-major) for conflict-free PV B-fragments
  transpose_bf16<<<dim3(Dm / 64, M / 64), 256, 0, stream>>>(Vb, Vtb, M, Dm);

  // causal attention: balanced pair {bx, 31-bx} per block
  mla_attn<<<dim3(T / 128, H, B), 256, 0, stream>>>(Qb, Kb, Vtb, AO, T);

  // output projection (fp32 out)
  gemm_bt<<<dim3(Dm / 128, M / 128), 256, 0, stream>>>(AO, WoT, nullptr, out, M, Dm, Dm);
  (void)Dh; (void)H;
}